// Round 2
// baseline (764.054 us; speedup 1.0000x reference)
//
#include <hip/hip_runtime.h>
#include <hip/hip_bf16.h>

// MultiScaleAttentionPE — MI355X round 1
// Runtime dtype detection (bf16 vs fp32 storage) + canonical fp32 staging.
// Compute kernels are unchanged vector-ALU GEMMs reading canonical fp32.

typedef __hip_bfloat16 bf16;

#define cN0 65536
#define cN1 16384
#define cN2 4096
#define cN3 1024
#define cN4 256

__device__ __forceinline__ float b2f(bf16 v) { return __bfloat162float(v); }

// ---------------- dtype detect ----------------
// Interpret first 1024 uint16 of xyz0 as bf16. Real bf16 N(0,1) data has
// exponent <= ~129; fp32 low-halves have uniform exponents -> flag fp32 if
// any exponent >= 138 (|v| >= 2048 or NaN/Inf).
__global__ void detect_kernel(const unsigned short* __restrict__ raw, int* __restrict__ flag) {
    __shared__ int bad;
    if (threadIdx.x == 0) bad = 0;
    __syncthreads();
    for (int i = threadIdx.x; i < 1024; i += 256) {
        int e = (raw[i] >> 7) & 0xFF;
        if (e >= 138) atomicOr(&bad, 1);
    }
    __syncthreads();
    if (threadIdx.x == 0) flag[0] = bad ? 1 : 0;
}

// ---------------- canonicalize all float tensors to fp32 ----------------
struct CanonArgs { const void* src[23]; };

__global__ void canon_kernel(CanonArgs a, const int* __restrict__ flag, float* __restrict__ dst) {
    const int sizes[23] = {196608, 768, 256,
                           768, 256, 768, 256, 768, 256, 768, 256, 768, 256,
                           131072, 256, 131072, 256, 131072, 256, 131072, 256, 131072, 256};
    int fp32 = flag[0];
    int gid = blockIdx.x * 256 + threadIdx.x;
    int off = 0;
#pragma unroll
    for (int s = 0; s < 23; ++s) {
        int n = sizes[s];
        if (gid >= off && gid < off + n) {
            int local = gid - off;
            float v = fp32 ? ((const float*)a.src[s])[local]
                           : b2f(((const bf16*)a.src[s])[local]);
            dst[gid] = v;
        }
        off += n;
    }
}

// ---------------- cls4 = column-max of f0[:256] ----------------
__global__ void cls4_kernel(const float* __restrict__ xyzf, const float* __restrict__ Wallf,
                            const float* __restrict__ ballf, float* __restrict__ cls4) {
    __shared__ float px[256], py[256], pz[256];
    int t = threadIdx.x;
    px[t] = xyzf[3 * t + 0];
    py[t] = xyzf[3 * t + 1];
    pz[t] = xyzf[3 * t + 2];
    __syncthreads();
    float w0 = Wallf[t], w1 = Wallf[256 + t], w2 = Wallf[512 + t];
    float b = ballf[t];
    float best = -3.402823466e38f;
    for (int i = 0; i < 256; ++i) {
        float v = fmaf(pz[i], w2, fmaf(py[i], w1, px[i] * w0)) + b;
        best = fmaxf(best, v);
    }
    cls4[t] = best;
}

// ---------------- 1-NN argmin ----------------
// Distance = (q2 - 2*dot) + r2 (reference's expanded form, same fp32 op order).
// 64 queries/block; 4 thread-partitions split the ref range; strict '<' keeps
// first index; cross-partition tie -> smaller index.
__global__ void nn_kernel(const float* __restrict__ xyzf, const int* __restrict__ idxQ,
                          const int* __restrict__ idxR, int nR, int* __restrict__ outK) {
    __shared__ __align__(16) float4 ref4[1024];
    __shared__ float redD[256];
    __shared__ int redI[256];
    int tid = threadIdx.x;
    int part = tid >> 6;
    int q = blockIdx.x * 64 + (tid & 63);
    int qi = idxQ[q];
    float qx = xyzf[3 * qi + 0];
    float qy = xyzf[3 * qi + 1];
    float qz = xyzf[3 * qi + 2];
    float q2 = (qx * qx + qy * qy) + qz * qz;
    float best = 3.402823466e38f;
    int bi = 0;
    for (int base = 0; base < nR; base += 1024) {
        int nt = min(1024, nR - base);
        __syncthreads();
        for (int t = tid; t < nt; t += 256) {
            int ri = idxR[base + t];
            float x = xyzf[3 * ri + 0];
            float y = xyzf[3 * ri + 1];
            float z = xyzf[3 * ri + 2];
            ref4[t] = make_float4(x, y, z, (x * x + y * y) + z * z);
        }
        __syncthreads();
        int seg = nt >> 2;
        int s0 = part * seg;
        for (int t = 0; t < seg; ++t) {
            float4 rp = ref4[s0 + t];
            float dot = (qx * rp.x + qy * rp.y) + qz * rp.z;
            float d = (q2 - 2.0f * dot) + rp.w;
            if (d < best) { best = d; bi = base + s0 + t; }
        }
    }
    redD[tid] = best;
    redI[tid] = bi;
    __syncthreads();
    if (part == 0) {
#pragma unroll
        for (int p = 1; p < 4; ++p) {
            float d = redD[tid + p * 64];
            int i2 = redI[tid + p * 64];
            if (d < best || (d == best && i2 < bi)) { best = d; bi = i2; }
        }
        outK[q] = bi;
    }
}

// ---------------- fused level kernel ----------------
// Row i of h (K=512): [ pe_prev[k_i] + (dxyz_i @ W + b) ; f0[i] ]; out = h @ P + pb.
// 64x64 output tile per block, 256 threads, 4x4 micro-tiles, K staged 32-wide.
__global__ __launch_bounds__(256) void level_kernel(
    const float* __restrict__ xyzf,
    const float* __restrict__ pe_prev,
    const int* __restrict__ kmap,
    const int* __restrict__ idxQ,
    const int* __restrict__ idxR,
    const float* __restrict__ W, const float* __restrict__ b,
    const float* __restrict__ Wall, const float* __restrict__ ball,
    const float* __restrict__ P, const float* __restrict__ pb,
    const int* __restrict__ flag, void* __restrict__ outv, size_t out_off,
    float* __restrict__ pe_out) {
    __shared__ float Wl[768], bl[256], Wal[768], bal[256], pbl[256];
    __shared__ __align__(16) float hA[64 * 33];   // [row][k] stride 33
    __shared__ __align__(16) float Pb[32 * 64];   // [k][col]
    __shared__ float rowD[64][3], rowX[64][3];
    __shared__ int rowK[64];

    int tid = threadIdx.x;
    int row0 = blockIdx.x * 64;
    int jb = blockIdx.y * 64;
    int fp32out = flag[0];

    for (int i = tid; i < 768; i += 256) { Wl[i] = W[i]; Wal[i] = Wall[i]; }
    bl[tid] = b[tid];
    bal[tid] = ball[tid];
    pbl[tid] = pb[tid];
    if (tid < 64) {
        int r = tid, row = row0 + r;
        float xx = xyzf[3 * row + 0];
        float yy = xyzf[3 * row + 1];
        float zz = xyzf[3 * row + 2];
        rowX[r][0] = xx; rowX[r][1] = yy; rowX[r][2] = zz;
        int k = kmap ? kmap[row] : 0;
        rowK[r] = k;
        float qx = xx, qy = yy, qz = zz;
        if (idxQ) {
            int qi = idxQ[row];
            qx = xyzf[3 * qi + 0];
            qy = xyzf[3 * qi + 1];
            qz = xyzf[3 * qi + 2];
        }
        float rx = 0.f, ry = 0.f, rz = 0.f;
        if (idxR) {
            int ri = idxR[k];
            rx = xyzf[3 * ri + 0];
            ry = xyzf[3 * ri + 1];
            rz = xyzf[3 * ri + 2];
        }
        rowD[r][0] = qx - rx; rowD[r][1] = qy - ry; rowD[r][2] = qz - rz;
    }
    __syncthreads();

    int rg = tid >> 4, cg = tid & 15;
    int r0 = rg * 4, j0 = cg * 4;
    float acc[4][4] = {};

    for (int kt = 0; kt < 16; ++kt) {
        int c0 = kt * 32;
        // build hA tile (64 rows x 32 k)
#pragma unroll
        for (int j = 0; j < 8; ++j) {
            int lin = j * 256 + tid;
            int r = lin >> 5, c = lin & 31;
            int cc = c0 + c;
            float v;
            if (cc < 256) {
                float dotb = fmaf(rowD[r][2], Wl[512 + cc],
                             fmaf(rowD[r][1], Wl[256 + cc], rowD[r][0] * Wl[cc])) + bl[cc];
                v = pe_prev[(size_t)rowK[r] * 256 + cc] + dotb;
            } else {
                int c2 = cc - 256;
                v = fmaf(rowX[r][2], Wal[512 + c2],
                    fmaf(rowX[r][1], Wal[256 + c2], rowX[r][0] * Wal[c2])) + bal[c2];
            }
            hA[r * 33 + c] = v;
        }
        // stage P tile (32 k x 64 cols), float4
#pragma unroll
        for (int j = 0; j < 2; ++j) {
            int lin = j * 256 + tid;          // 0..511
            int c = lin >> 4, qq = (lin & 15) * 4;
            float4 p = *(const float4*)&P[(size_t)(c0 + c) * 256 + jb + qq];
            *(float4*)&Pb[c * 64 + qq] = p;
        }
        __syncthreads();
#pragma unroll
        for (int c = 0; c < 32; ++c) {
            float a0 = hA[(r0 + 0) * 33 + c];
            float a1 = hA[(r0 + 1) * 33 + c];
            float a2 = hA[(r0 + 2) * 33 + c];
            float a3 = hA[(r0 + 3) * 33 + c];
            float4 p = *(const float4*)&Pb[c * 64 + j0];
            acc[0][0] = fmaf(a0, p.x, acc[0][0]); acc[0][1] = fmaf(a0, p.y, acc[0][1]);
            acc[0][2] = fmaf(a0, p.z, acc[0][2]); acc[0][3] = fmaf(a0, p.w, acc[0][3]);
            acc[1][0] = fmaf(a1, p.x, acc[1][0]); acc[1][1] = fmaf(a1, p.y, acc[1][1]);
            acc[1][2] = fmaf(a1, p.z, acc[1][2]); acc[1][3] = fmaf(a1, p.w, acc[1][3]);
            acc[2][0] = fmaf(a2, p.x, acc[2][0]); acc[2][1] = fmaf(a2, p.y, acc[2][1]);
            acc[2][2] = fmaf(a2, p.z, acc[2][2]); acc[2][3] = fmaf(a2, p.w, acc[2][3]);
            acc[3][0] = fmaf(a3, p.x, acc[3][0]); acc[3][1] = fmaf(a3, p.y, acc[3][1]);
            acc[3][2] = fmaf(a3, p.z, acc[3][2]); acc[3][3] = fmaf(a3, p.w, acc[3][3]);
        }
        __syncthreads();
    }

#pragma unroll
    for (int u = 0; u < 4; ++u) {
#pragma unroll
        for (int v = 0; v < 4; ++v) {
            int row = row0 + r0 + u;
            int col = jb + j0 + v;
            size_t idx = (size_t)row * 256 + col;
            float val = acc[u][v] + pbl[col];
            if (fp32out) ((float*)outv)[out_off + idx] = val;
            else         ((bf16*)outv)[out_off + idx] = __float2bfloat16(val);
            if (pe_out) pe_out[idx] = val;
        }
    }
}

extern "C" void kernel_launch(void* const* d_in, const int* in_sizes, int n_in,
                              void* d_out, int out_size, void* d_ws, size_t ws_size,
                              hipStream_t stream) {
    const int* idx0 = (const int*)d_in[1];
    const int* idx1 = (const int*)d_in[2];
    const int* idx2 = (const int*)d_in[3];
    const int* idx3 = (const int*)d_in[4];
    const int* idx4 = (const int*)d_in[5];

    // workspace layout
    float* ws = (float*)d_ws;
    int* flag = (int*)ws;            // 64 floats reserved
    float* p = ws + 64;
    float* xyzf = p;  p += 196608;
    float* Wallf = p; p += 768;
    float* ballf = p; p += 256;
    float* Wf[5]; float* bff[5];
    for (int i = 0; i < 5; ++i) { Wf[i] = p; p += 768; bff[i] = p; p += 256; }
    float* Pf[5]; float* pbf[5];
    for (int i = 0; i < 5; ++i) { Pf[i] = p; p += 131072; pbf[i] = p; p += 256; }
    float* cls4 = p;  p += 256;
    float* pe4f = p;  p += 256 * 256;
    float* pe3f = p;  p += 1024 * 256;
    float* pe2f = p;  p += 4096 * 256;
    float* pe1f = p;  p += 16384 * 256;
    int* k34 = (int*)p;
    int* k23 = k34 + 1024;
    int* k12 = k23 + 4096;

    detect_kernel<<<1, 256, 0, stream>>>((const unsigned short*)d_in[0], flag);

    CanonArgs ca;
    ca.src[0] = d_in[0];                    // xyz0
    ca.src[1] = d_in[6];                    // W_all
    ca.src[2] = d_in[7];                    // b_all
    for (int i = 0; i < 10; ++i) ca.src[3 + i] = d_in[8 + i];    // W4..b0
    for (int i = 0; i < 10; ++i) ca.src[13 + i] = d_in[18 + i];  // P4..pb0
    canon_kernel<<<3357, 256, 0, stream>>>(ca, flag, ws + 64);

    cls4_kernel<<<1, 256, 0, stream>>>(xyzf, Wallf, ballf, cls4);
    nn_kernel<<<cN3 / 64, 256, 0, stream>>>(xyzf, idx3, idx4, cN4, k34);
    nn_kernel<<<cN2 / 64, 256, 0, stream>>>(xyzf, idx2, idx3, cN3, k23);
    nn_kernel<<<cN1 / 64, 256, 0, stream>>>(xyzf, idx1, idx2, cN2, k12);

    // output element offsets (in elements of the output dtype)
    const size_t o4 = 0;
    const size_t o3 = (size_t)cN4 * 256;
    const size_t o2 = o3 + (size_t)cN3 * 256;
    const size_t o1 = o2 + (size_t)cN2 * 256;
    const size_t o0 = o1 + (size_t)cN1 * 256;

    level_kernel<<<dim3(cN4 / 64, 4), 256, 0, stream>>>(
        xyzf, cls4, nullptr, idx4, nullptr, Wf[0], bff[0], Wallf, ballf,
        Pf[0], pbf[0], flag, d_out, o4, pe4f);
    level_kernel<<<dim3(cN3 / 64, 4), 256, 0, stream>>>(
        xyzf, pe4f, k34, idx3, idx4, Wf[1], bff[1], Wallf, ballf,
        Pf[1], pbf[1], flag, d_out, o3, pe3f);
    level_kernel<<<dim3(cN2 / 64, 4), 256, 0, stream>>>(
        xyzf, pe3f, k23, idx2, idx3, Wf[2], bff[2], Wallf, ballf,
        Pf[2], pbf[2], flag, d_out, o2, pe2f);
    level_kernel<<<dim3(cN1 / 64, 4), 256, 0, stream>>>(
        xyzf, pe2f, k12, idx1, idx2, Wf[3], bff[3], Wallf, ballf,
        Pf[3], pbf[3], flag, d_out, o1, pe1f);
    level_kernel<<<dim3(cN0 / 64, 4), 256, 0, stream>>>(
        xyzf, pe1f, idx0, nullptr, idx1, Wf[4], bff[4], Wallf, ballf,
        Pf[4], pbf[4], flag, d_out, o0, nullptr);
}

// Round 3
// 358.221 us; speedup vs baseline: 2.1329x; 2.1329x over previous
//
#include <hip/hip_runtime.h>
#include <hip/hip_bf16.h>

// MultiScaleAttentionPE — MI355X round 3
// MFMA (bf16 16x16x32) level GEMMs; fp32-exact NN/argmin and cls4 preserved.

typedef __hip_bfloat16 bf16;
typedef unsigned short ushort_t;
typedef __attribute__((ext_vector_type(8))) short short8;
typedef __attribute__((ext_vector_type(4))) float float4v;

#define cN0 65536
#define cN1 16384
#define cN2 4096
#define cN3 1024
#define cN4 256

__device__ __forceinline__ float b2f(bf16 v) { return __bfloat162float(v); }

// RNE float -> bf16 bits (values are finite; no NaN path needed)
__device__ __forceinline__ ushort_t f2b(float v) {
    union { float f; unsigned u; } x; x.f = v;
    unsigned r = x.u + 0x7FFF + ((x.u >> 16) & 1);
    return (ushort_t)(r >> 16);
}

// ---------------- dtype detect (bf16 vs fp32 storage) ----------------
__global__ void detect_kernel(const unsigned short* __restrict__ raw, int* __restrict__ flag) {
    __shared__ int bad;
    if (threadIdx.x == 0) bad = 0;
    __syncthreads();
    for (int i = threadIdx.x; i < 1024; i += 256) {
        int e = (raw[i] >> 7) & 0xFF;
        if (e >= 138) atomicOr(&bad, 1);
    }
    __syncthreads();
    if (threadIdx.x == 0) flag[0] = bad ? 1 : 0;
}

// ---------------- canonicalize all float tensors to fp32 ----------------
struct CanonArgs { const void* src[23]; };

__global__ void canon_kernel(CanonArgs a, const int* __restrict__ flag, float* __restrict__ dst) {
    const int sizes[23] = {196608, 768, 256,
                           768, 256, 768, 256, 768, 256, 768, 256, 768, 256,
                           131072, 256, 131072, 256, 131072, 256, 131072, 256, 131072, 256};
    int fp32 = flag[0];
    int gid = blockIdx.x * 256 + threadIdx.x;
    int off = 0;
#pragma unroll
    for (int s = 0; s < 23; ++s) {
        int n = sizes[s];
        if (gid >= off && gid < off + n) {
            int local = gid - off;
            float v = fp32 ? ((const float*)a.src[s])[local]
                           : b2f(((const bf16*)a.src[s])[local]);
            dst[gid] = v;
        }
        off += n;
    }
}

// ---------------- P -> P^T bf16  ([512][256] fp32 -> [256][512] bf16) ----------------
__global__ void prep_pt(const float* __restrict__ Pf0, ushort_t* __restrict__ PTb) {
    int level = blockIdx.x;
    int kb = blockIdx.y;
    const float* P = Pf0 + (size_t)level * 131328;   // P (131072) + pb (256) stride
    ushort_t* PT = PTb + (size_t)level * 131072;
    int n = threadIdx.x;
    for (int kk = 0; kk < 64; ++kk) {
        int k = kb * 64 + kk;
        PT[(size_t)n * 512 + k] = f2b(P[(size_t)k * 256 + n]);
    }
}

// ---------------- cls4 = column-max of f0[:256] ----------------
__global__ void cls4_kernel(const float* __restrict__ xyzf, const float* __restrict__ Wallf,
                            const float* __restrict__ ballf, float* __restrict__ cls4) {
    __shared__ float px[256], py[256], pz[256];
    int t = threadIdx.x;
    px[t] = xyzf[3 * t + 0];
    py[t] = xyzf[3 * t + 1];
    pz[t] = xyzf[3 * t + 2];
    __syncthreads();
    float w0 = Wallf[t], w1 = Wallf[256 + t], w2 = Wallf[512 + t];
    float b = ballf[t];
    float best = -3.402823466e38f;
    for (int i = 0; i < 256; ++i) {
        float v = fmaf(pz[i], w2, fmaf(py[i], w1, px[i] * w0)) + b;
        best = fmaxf(best, v);
    }
    cls4[t] = best;
}

// ---------------- 1-NN argmin (fp32-exact, reference op order) ----------------
__global__ void nn_kernel(const float* __restrict__ xyzf, const int* __restrict__ idxQ,
                          const int* __restrict__ idxR, int nR, int* __restrict__ outK) {
    __shared__ __align__(16) float4 ref4[1024];
    __shared__ float redD[256];
    __shared__ int redI[256];
    int tid = threadIdx.x;
    int part = tid >> 6;
    int q = blockIdx.x * 64 + (tid & 63);
    int qi = idxQ[q];
    float qx = xyzf[3 * qi + 0];
    float qy = xyzf[3 * qi + 1];
    float qz = xyzf[3 * qi + 2];
    float q2 = (qx * qx + qy * qy) + qz * qz;
    float best = 3.402823466e38f;
    int bi = 0;
    for (int base = 0; base < nR; base += 1024) {
        int nt = min(1024, nR - base);
        __syncthreads();
        for (int t = tid; t < nt; t += 256) {
            int ri = idxR[base + t];
            float x = xyzf[3 * ri + 0];
            float y = xyzf[3 * ri + 1];
            float z = xyzf[3 * ri + 2];
            ref4[t] = make_float4(x, y, z, (x * x + y * y) + z * z);
        }
        __syncthreads();
        int seg = nt >> 2;
        int s0 = part * seg;
        for (int t = 0; t < seg; ++t) {
            float4 rp = ref4[s0 + t];
            float dot = (qx * rp.x + qy * rp.y) + qz * rp.z;
            float d = (q2 - 2.0f * dot) + rp.w;
            if (d < best) { best = d; bi = base + s0 + t; }
        }
    }
    redD[tid] = best;
    redI[tid] = bi;
    __syncthreads();
    if (part == 0) {
#pragma unroll
        for (int p = 1; p < 4; ++p) {
            float d = redD[tid + p * 64];
            int i2 = redI[tid + p * 64];
            if (d < best || (d == best && i2 < bi)) { best = d; bi = i2; }
        }
        outK[q] = bi;
    }
}

// ---------------- MFMA level kernel ----------------
// Block: 128 rows x 256 cols, 512 threads (8 waves, each a 64x64 tile).
// h row (K=512): [ pe_prev[k_i] + dxyz_i @ W + b ; rowX_i @ Wall + ball ]
// built in fp32, rounded to bf16 into LDS; P^T staged bf16; 16x16x32 MFMA.
__global__ __launch_bounds__(512, 4) void level_mfma(
    const float* __restrict__ xyzf,
    const float* __restrict__ pe_prev,
    const int* __restrict__ kmap,
    const int* __restrict__ idxQ,
    const int* __restrict__ idxR,
    const float* __restrict__ W, const float* __restrict__ b,
    const float* __restrict__ Wall, const float* __restrict__ ball,
    const ushort_t* __restrict__ PT, const float* __restrict__ pb,
    const int* __restrict__ flag, void* __restrict__ outv, size_t out_off,
    float* __restrict__ pe_out) {
    __shared__ float Wl[768], bl[256], Wal[768], bal[256], pbl[256];
    __shared__ float rowD[128][3], rowX[128][3];
    __shared__ int rowK[128];
    __shared__ __align__(16) ushort_t A_lds[128 * 40];   // [row][k] stride 40 (BK=32 +8 pad)
    __shared__ __align__(16) ushort_t B_lds[256 * 40];   // [col][k] stride 40

    int tid = threadIdx.x;
    int row0 = blockIdx.x * 128;
    int fp32out = flag[0];

    for (int i = tid; i < 768; i += 512) { Wl[i] = W[i]; Wal[i] = Wall[i]; }
    if (tid < 256) { bl[tid] = b[tid]; bal[tid] = ball[tid]; pbl[tid] = pb[tid]; }
    if (tid < 128) {
        int r = tid, row = row0 + r;
        float xx = xyzf[3 * row + 0];
        float yy = xyzf[3 * row + 1];
        float zz = xyzf[3 * row + 2];
        rowX[r][0] = xx; rowX[r][1] = yy; rowX[r][2] = zz;
        int k = kmap ? kmap[row] : 0;
        rowK[r] = k;
        float qx = xx, qy = yy, qz = zz;
        if (idxQ) {
            int qi = idxQ[row];
            qx = xyzf[3 * qi + 0];
            qy = xyzf[3 * qi + 1];
            qz = xyzf[3 * qi + 2];
        }
        float rx = 0.f, ry = 0.f, rz = 0.f;
        if (idxR) {
            int ri = idxR[k];
            rx = xyzf[3 * ri + 0];
            ry = xyzf[3 * ri + 1];
            rz = xyzf[3 * ri + 2];
        }
        rowD[r][0] = qx - rx; rowD[r][1] = qy - ry; rowD[r][2] = qz - rz;
    }
    __syncthreads();

    int wave = tid >> 6;
    int lane = tid & 63;
    int quad = lane >> 4;
    int l16 = lane & 15;
    int wr = (wave >> 2) * 64;     // 0 / 64
    int wc = (wave & 3) * 64;      // 0 / 64 / 128 / 192

    float4v acc[4][4];
#pragma unroll
    for (int mt = 0; mt < 4; ++mt)
#pragma unroll
        for (int nt = 0; nt < 4; ++nt) acc[mt][nt] = (float4v){0.f, 0.f, 0.f, 0.f};

    for (int kt = 0; kt < 16; ++kt) {
        int c0 = kt * 32;
        // ---- build A tile (128 rows x 32 k, bf16) ----
        if (c0 < 256) {
#pragma unroll
            for (int it = 0; it < 2; ++it) {
                int lin = it * 512 + tid;          // 0..1023
                int r = lin >> 3, g = lin & 7;
                int k0 = c0 + g * 4;
                float4 pv = *(const float4*)(pe_prev + (size_t)rowK[r] * 256 + k0);
                float dx = rowD[r][0], dy = rowD[r][1], dz = rowD[r][2];
                float v0 = pv.x + (fmaf(dz, Wl[512 + k0 + 0], fmaf(dy, Wl[256 + k0 + 0], dx * Wl[k0 + 0])) + bl[k0 + 0]);
                float v1 = pv.y + (fmaf(dz, Wl[512 + k0 + 1], fmaf(dy, Wl[256 + k0 + 1], dx * Wl[k0 + 1])) + bl[k0 + 1]);
                float v2 = pv.z + (fmaf(dz, Wl[512 + k0 + 2], fmaf(dy, Wl[256 + k0 + 2], dx * Wl[k0 + 2])) + bl[k0 + 2]);
                float v3 = pv.w + (fmaf(dz, Wl[512 + k0 + 3], fmaf(dy, Wl[256 + k0 + 3], dx * Wl[k0 + 3])) + bl[k0 + 3]);
                ushort4 pk = make_ushort4(f2b(v0), f2b(v1), f2b(v2), f2b(v3));
                *(ushort4*)&A_lds[r * 40 + g * 4] = pk;
            }
        } else {
#pragma unroll
            for (int it = 0; it < 2; ++it) {
                int lin = it * 512 + tid;
                int r = lin >> 3, g = lin & 7;
                int k0 = c0 - 256 + g * 4;
                float xx = rowX[r][0], yy = rowX[r][1], zz = rowX[r][2];
                float v0 = fmaf(zz, Wal[512 + k0 + 0], fmaf(yy, Wal[256 + k0 + 0], xx * Wal[k0 + 0])) + bal[k0 + 0];
                float v1 = fmaf(zz, Wal[512 + k0 + 1], fmaf(yy, Wal[256 + k0 + 1], xx * Wal[k0 + 1])) + bal[k0 + 1];
                float v2 = fmaf(zz, Wal[512 + k0 + 2], fmaf(yy, Wal[256 + k0 + 2], xx * Wal[k0 + 2])) + bal[k0 + 2];
                float v3 = fmaf(zz, Wal[512 + k0 + 3], fmaf(yy, Wal[256 + k0 + 3], xx * Wal[k0 + 3])) + bal[k0 + 3];
                ushort4 pk = make_ushort4(f2b(v0), f2b(v1), f2b(v2), f2b(v3));
                *(ushort4*)&A_lds[r * 40 + g * 4] = pk;
            }
        }
        // ---- stage B tile (256 cols x 32 k, bf16, from P^T) ----
#pragma unroll
        for (int it = 0; it < 2; ++it) {
            int lin = it * 512 + tid;              // 0..1023
            int n = lin >> 2, g = lin & 3;
            uint4 v = *(const uint4*)(PT + (size_t)n * 512 + c0 + g * 8);
            *(uint4*)&B_lds[n * 40 + g * 8] = v;
        }
        __syncthreads();
        // ---- MFMA: one 32-k chunk ----
        int kk = quad * 8;
        short8 afr[4], bfr[4];
#pragma unroll
        for (int mt = 0; mt < 4; ++mt)
            afr[mt] = *(const short8*)&A_lds[(wr + mt * 16 + l16) * 40 + kk];
#pragma unroll
        for (int nt = 0; nt < 4; ++nt)
            bfr[nt] = *(const short8*)&B_lds[(wc + nt * 16 + l16) * 40 + kk];
#pragma unroll
        for (int mt = 0; mt < 4; ++mt)
#pragma unroll
            for (int nt = 0; nt < 4; ++nt)
                acc[mt][nt] = __builtin_amdgcn_mfma_f32_16x16x32_bf16(
                    afr[mt], bfr[nt], acc[mt][nt], 0, 0, 0);
        __syncthreads();
    }

    // ---- epilogue: D row = quad*4+reg, col = lane&15 ----
#pragma unroll
    for (int mt = 0; mt < 4; ++mt) {
#pragma unroll
        for (int nt = 0; nt < 4; ++nt) {
            int col = wc + nt * 16 + l16;
            float pbv = pbl[col];
#pragma unroll
            for (int reg = 0; reg < 4; ++reg) {
                int row = row0 + wr + mt * 16 + quad * 4 + reg;
                size_t idx = (size_t)row * 256 + col;
                float val = acc[mt][nt][reg] + pbv;
                if (fp32out) ((float*)outv)[out_off + idx] = val;
                else         ((bf16*)outv)[out_off + idx] = __float2bfloat16(val);
                if (pe_out) pe_out[idx] = val;
            }
        }
    }
}

extern "C" void kernel_launch(void* const* d_in, const int* in_sizes, int n_in,
                              void* d_out, int out_size, void* d_ws, size_t ws_size,
                              hipStream_t stream) {
    const int* idx0 = (const int*)d_in[1];
    const int* idx1 = (const int*)d_in[2];
    const int* idx2 = (const int*)d_in[3];
    const int* idx3 = (const int*)d_in[4];
    const int* idx4 = (const int*)d_in[5];

    // workspace layout
    float* ws = (float*)d_ws;
    int* flag = (int*)ws;            // 64 floats reserved
    float* p = ws + 64;
    float* xyzf = p;  p += 196608;
    float* Wallf = p; p += 768;
    float* ballf = p; p += 256;
    float* Wf[5]; float* bff[5];
    for (int i = 0; i < 5; ++i) { Wf[i] = p; p += 768; bff[i] = p; p += 256; }
    float* Pf[5]; float* pbf[5];
    for (int i = 0; i < 5; ++i) { Pf[i] = p; p += 131072; pbf[i] = p; p += 256; }
    float* cls4 = p;  p += 256;
    float* pe4f = p;  p += 256 * 256;
    float* pe3f = p;  p += 1024 * 256;
    float* pe2f = p;  p += 4096 * 256;
    float* pe1f = p;  p += 16384 * 256;
    int* k34 = (int*)p; p += 1024;
    int* k23 = (int*)p; p += 4096;
    int* k12 = (int*)p; p += 16384;
    ushort_t* PTb = (ushort_t*)p;    // 5 * 131072 bf16

    detect_kernel<<<1, 256, 0, stream>>>((const unsigned short*)d_in[0], flag);

    CanonArgs ca;
    ca.src[0] = d_in[0];
    ca.src[1] = d_in[6];
    ca.src[2] = d_in[7];
    for (int i = 0; i < 10; ++i) ca.src[3 + i] = d_in[8 + i];
    for (int i = 0; i < 10; ++i) ca.src[13 + i] = d_in[18 + i];
    canon_kernel<<<3357, 256, 0, stream>>>(ca, flag, ws + 64);

    prep_pt<<<dim3(5, 8), 256, 0, stream>>>(Pf[0], PTb);
    cls4_kernel<<<1, 256, 0, stream>>>(xyzf, Wallf, ballf, cls4);
    nn_kernel<<<cN3 / 64, 256, 0, stream>>>(xyzf, idx3, idx4, cN4, k34);
    nn_kernel<<<cN2 / 64, 256, 0, stream>>>(xyzf, idx2, idx3, cN3, k23);
    nn_kernel<<<cN1 / 64, 256, 0, stream>>>(xyzf, idx1, idx2, cN2, k12);

    const size_t o4 = 0;
    const size_t o3 = (size_t)cN4 * 256;
    const size_t o2 = o3 + (size_t)cN3 * 256;
    const size_t o1 = o2 + (size_t)cN2 * 256;
    const size_t o0 = o1 + (size_t)cN1 * 256;

    level_mfma<<<cN4 / 128, 512, 0, stream>>>(
        xyzf, cls4, nullptr, idx4, nullptr, Wf[0], bff[0], Wallf, ballf,
        PTb + 0 * 131072, pbf[0], flag, d_out, o4, pe4f);
    level_mfma<<<cN3 / 128, 512, 0, stream>>>(
        xyzf, pe4f, k34, idx3, idx4, Wf[1], bff[1], Wallf, ballf,
        PTb + 1 * 131072, pbf[1], flag, d_out, o3, pe3f);
    level_mfma<<<cN2 / 128, 512, 0, stream>>>(
        xyzf, pe3f, k23, idx2, idx3, Wf[2], bff[2], Wallf, ballf,
        PTb + 2 * 131072, pbf[2], flag, d_out, o2, pe2f);
    level_mfma<<<cN1 / 128, 512, 0, stream>>>(
        xyzf, pe2f, k12, idx1, idx2, Wf[3], bff[3], Wallf, ballf,
        PTb + 3 * 131072, pbf[3], flag, d_out, o1, pe1f);
    level_mfma<<<cN0 / 128, 512, 0, stream>>>(
        xyzf, pe1f, idx0, nullptr, idx1, Wf[4], bff[4], Wallf, ballf,
        PTb + 4 * 131072, pbf[4], flag, d_out, o0, nullptr);
}